// Round 3
// baseline (450.867 us; speedup 1.0000x reference)
//
#include <hip/hip_runtime.h>

#define NCELL 24576      // 128*192 feature cells
#define NTOT  221184     // NCELL * 9
#define NBIN  65536
#define TOPN  6000
#define POSTN 300
#define CAP   8192       // compaction capacity (pow2 for bitonic)
#define NPADR 6016       // padded candidate count (94 words of 64)
#define NW    94         // suppression-mask words per row

// ---------------- decode anchors + scores, build sort keys, histogram ----------------
__global__ void decode_kernel(const float* __restrict__ scores,
                              const float* __restrict__ deltas,
                              const float* __restrict__ iminfo,
                              float4* __restrict__ boxes,
                              unsigned* __restrict__ skeys,
                              unsigned* __restrict__ hist) {
#pragma clang fp contract(off)
    int c = blockIdx.x * blockDim.x + threadIdx.x;
    if (c >= NCELL) return;
    const float AW[9] = {184.f,368.f,736.f,128.f,256.f,512.f, 88.f,176.f,352.f};
    const float AH[9] = { 96.f,192.f,384.f,128.f,256.f,512.f,176.f,352.f,704.f};
    float sx = (float)((c >> 7) << 4);   // (c/128)*16  -- 'ij' meshgrid quirk
    float sy = (float)((c & 127) << 4);  // (c%128)*16
    float imh = iminfo[0], imw = iminfo[1], ims = iminfo[2];
    float xhi = imw - 1.0f, yhi = imh - 1.0f;
    float ms = 16.0f * ims;
    float ctrx = sx + 8.0f, ctry = sy + 8.0f;
    const float* sbase = scores + 9 * NCELL + c;
    const float* dbase = deltas + c;
#pragma unroll
    for (int a = 0; a < 9; ++a) {
        float sc = sbase[a * NCELL];
        float dx = dbase[(4 * a + 0) * NCELL];
        float dy = dbase[(4 * a + 1) * NCELL];
        float dw = dbase[(4 * a + 2) * NCELL];
        float dh = dbase[(4 * a + 3) * NCELL];
        float pcx = dx * AW[a] + ctrx;
        float pcy = dy * AH[a] + ctry;
        float pw = expf(dw) * AW[a];
        float ph = expf(dh) * AH[a];
        float x1 = pcx - 0.5f * pw;
        float y1 = pcy - 0.5f * ph;
        float x2 = pcx + 0.5f * pw;
        float y2 = pcy + 0.5f * ph;
        x1 = fminf(fmaxf(x1, 0.0f), xhi);
        x2 = fminf(fmaxf(x2, 0.0f), xhi);
        y1 = fminf(fmaxf(y1, 0.0f), yhi);
        y2 = fminf(fmaxf(y2, 0.0f), yhi);
        bool valid = ((x2 - x1 + 1.0f) >= ms) && ((y2 - y1 + 1.0f) >= ms);
        unsigned u = __float_as_uint(sc);
        unsigned key = (u & 0x80000000u) ? ~u : (u | 0x80000000u);
        if (!valid) key = 0x007FFFFFu;   // sort key of -inf
        boxes[a * NCELL + c] = make_float4(x1, y1, x2, y2);
        skeys[a * NCELL + c] = key;
        atomicAdd(&hist[key >> 16], 1u);
    }
}

// ---------------- find threshold bin T: cum(>T) < 6000 <= cum(>=T) ----------------
__global__ void thresh_kernel(const unsigned* __restrict__ hist, unsigned* __restrict__ meta) {
    __shared__ unsigned csum[256];
    __shared__ unsigned sB, sAbove;
    int tid = threadIdx.x;
    const uint4* h4 = (const uint4*)hist;
    unsigned s = 0;
#pragma unroll 8
    for (int q = 0; q < 64; ++q) {
        uint4 u = h4[tid * 64 + q];
        s += u.x + u.y + u.z + u.w;
    }
    csum[tid] = s;
    __syncthreads();
    if (tid < 64) {
        int lane = tid;
        unsigned c0 = csum[lane * 4 + 0], c1 = csum[lane * 4 + 1];
        unsigned c2 = csum[lane * 4 + 2], c3 = csum[lane * 4 + 3];
        unsigned ls = c0 + c1 + c2 + c3;
        unsigned v = ls;
#pragma unroll
        for (int o = 1; o < 64; o <<= 1) {
            unsigned t = __shfl_down(v, o, 64);
            if (lane + o < 64) v += t;
        }
        unsigned sufExcl = v - ls;   // sum over coarse bins of lanes > lane
        unsigned a3 = sufExcl;
        unsigned a2 = a3 + c3;
        unsigned a1 = a2 + c2;
        unsigned a0 = a1 + c1;
        if (a0 < TOPN && a0 + c0 >= TOPN) { sB = lane * 4 + 0; sAbove = a0; }
        if (a1 < TOPN && a1 + c1 >= TOPN) { sB = lane * 4 + 1; sAbove = a1; }
        if (a2 < TOPN && a2 + c2 >= TOPN) { sB = lane * 4 + 2; sAbove = a2; }
        if (a3 < TOPN && a3 + c3 >= TOPN) { sB = lane * 4 + 3; sAbove = a3; }
    }
    __syncthreads();
    if (tid < 64) {
        int lane = tid;
        unsigned B = sB, above = sAbove;
        uint4 f = h4[B * 64 + lane];       // fine bins B*256 + lane*4 + (0..3)
        unsigned ls = f.x + f.y + f.z + f.w;
        unsigned v = ls;
#pragma unroll
        for (int o = 1; o < 64; o <<= 1) {
            unsigned t = __shfl_down(v, o, 64);
            if (lane + o < 64) v += t;
        }
        unsigned sufExcl = v - ls;
        unsigned b3 = above + sufExcl;
        unsigned b2 = b3 + f.w;
        unsigned b1 = b2 + f.z;
        unsigned b0 = b1 + f.y;
        unsigned base2 = B * 256 + lane * 4;
        if (b0 < TOPN && b0 + f.x >= TOPN) meta[1] = base2 + 0;
        if (b1 < TOPN && b1 + f.y >= TOPN) meta[1] = base2 + 1;
        if (b2 < TOPN && b2 + f.z >= TOPN) meta[1] = base2 + 2;
        if (b3 < TOPN && b3 + f.w >= TOPN) meta[1] = base2 + 3;
    }
}

// ---------------- compact all candidates with key_hi >= T ----------------
__global__ void compact_kernel(const unsigned* __restrict__ skeys,
                               unsigned* __restrict__ meta,
                               unsigned long long* __restrict__ cbuf) {
    int m = blockIdx.x * blockDim.x + threadIdx.x;
    if (m >= NTOT) return;
    unsigned T = meta[1];
    unsigned sk = skeys[m];
    if ((sk >> 16) >= T) {
        unsigned pos = atomicAdd(&meta[0], 1u);
        if (pos < CAP) {
            unsigned n = (unsigned)((m % NCELL) * 9 + (m / NCELL));  // original flat index
            cbuf[pos] = ((unsigned long long)sk << 32) | (unsigned long long)(~n);
        }
    }
}

// ---------------- bitonic sort (desc) + emit sorted boxes + initial mask ----------------
__global__ __launch_bounds__(1024) void sort_kernel(const float4* __restrict__ boxes,
                                                    const unsigned* __restrict__ meta,
                                                    const unsigned long long* __restrict__ cbuf,
                                                    float4* __restrict__ sortedbox,
                                                    unsigned long long* __restrict__ initmask) {
    __shared__ __align__(16) unsigned long long keys[CAP];   // 64 KB
    int tid = threadIdx.x;
    unsigned count = meta[0];
    if (count > (unsigned)CAP) count = CAP;

    for (int idx = tid; idx < CAP; idx += 1024)
        keys[idx] = (idx < (int)count) ? cbuf[idx] : 0ULL;
    __syncthreads();

    // bitonic sort, descending (key = score_key:~index -> stable by index)
    for (int k = 2; k <= CAP; k <<= 1) {
        for (int j = k >> 1; j > 0; j >>= 1) {
            for (int t = tid; t < (CAP >> 1); t += 1024) {
                int i = ((t & ~(j - 1)) << 1) | (t & (j - 1));
                int ixj = i | j;
                unsigned long long a = keys[i], b = keys[ixj];
                bool up = ((i & k) == 0);
                if ((a < b) == up) { keys[i] = b; keys[ixj] = a; }
            }
            __syncthreads();
        }
    }

    // emit sortedbox[0..NPADR) and initmask (bit set = pre-suppressed/invalid)
#pragma unroll
    for (int p = 0; p < 6; ++p) {
        int r = tid + (p << 10);
        bool valid = false;
        if (r < NPADR) {
            float4 bb = make_float4(0.f, 0.f, 0.f, 0.f);
            unsigned long long kk = keys[r];
            unsigned skhi = (unsigned)(kk >> 32);
            if (r < (int)count && r < TOPN && skhi != 0x007FFFFFu) {
                unsigned n = ~(unsigned)kk;
                unsigned m = (n % 9u) * (unsigned)NCELL + (n / 9u);
                bb = boxes[m];
                valid = true;
            }
            sortedbox[r] = bb;
        }
        unsigned long long word = ~__ballot(valid);
        int W = (tid >> 6) + (p << 4);
        if ((tid & 63) == 0 && W < NW) initmask[W] = word;
    }
}

// ---------------- all-pairs suppression matrix: rowmat[i][w] bits j>i with iou>0.7 ----------------
__global__ __launch_bounds__(256) void matrix_kernel(const float4* __restrict__ sortedbox,
                                                     unsigned long long* __restrict__ rowmat) {
#pragma clang fp contract(off)
    __shared__ float4 rb[16];
    __shared__ float ra[16];
    int tid = threadIdx.x;
    int r0 = blockIdx.x * 16;
    if (tid < 16) {
        float4 v = sortedbox[r0 + tid];
        rb[tid] = v;
        ra[tid] = (v.z - v.x) * (v.w - v.y);
    }
    __syncthreads();
    int wave = tid >> 6, lane = tid & 63;
    for (int w = wave; w < NW; w += 4) {
        int j = (w << 6) + lane;
        float4 cb = sortedbox[j];
        float ca = (cb.z - cb.x) * (cb.w - cb.y);
#pragma unroll 4
        for (int rr = 0; rr < 16; ++rr) {
            int i = r0 + rr;
            if (((w << 6) + 63) <= i) {          // whole word is j<=i -> zero row word
                if (lane == 0) rowmat[(size_t)i * NW + w] = 0ULL;
                continue;
            }
            float4 bi = rb[rr];
            float ai = ra[rr];
            float iw = fminf(bi.z, cb.z) - fmaxf(bi.x, cb.x);
            float ih = fminf(bi.w, cb.w) - fmaxf(bi.y, cb.y);
            iw = fmaxf(iw, 0.0f);
            ih = fmaxf(ih, 0.0f);
            float inter = iw * ih;
            float denom = fmaxf(ai + ca - inter, 1e-9f);
            bool sup = (j > i) && (inter / denom > 0.7f);
            unsigned long long word = __ballot(sup);
            if (lane == 0) rowmat[(size_t)i * NW + w] = word;
        }
    }
}

// ---------------- greedy scan, batched per 64-block (one wave) + output ----------------
__global__ __launch_bounds__(64) void scan_kernel(const unsigned long long* __restrict__ rowmat,
                                                  const float4* __restrict__ sortedbox,
                                                  const unsigned long long* __restrict__ initmask,
                                                  float* __restrict__ out) {
    __shared__ int keptArr[POSTN];
    int lane = threadIdx.x;
    // suppression mask distributed: lane l holds words l and 64+l
    unsigned long long m0 = initmask[lane];
    unsigned long long m1 = (lane < NW - 64) ? initmask[64 + lane] : ~0ULL;
    int kept = 0;
    for (int w = 0; w < NW; ++w) {
        unsigned long long mw = (w < 64) ? __shfl(m0, w, 64) : __shfl(m1, w - 64, 64);
        unsigned long long live = ~mw;
        while (live) {
            // select up to 8 lowest live bits as the candidate batch (wave-uniform)
            int bpos[8];
            int nb = 0;
            unsigned long long t = live;
#pragma unroll
            for (int s = 0; s < 8; ++s) {
                if (t) { bpos[s] = __ffsll(t) - 1; t &= t - 1; nb = s + 1; }
                else bpos[s] = 0;
            }
            // batch-load all candidate rows (independent -> one latency)
            unsigned long long rlo[8], rhi[8];
#pragma unroll
            for (int s = 0; s < 8; ++s) {
                if (s < nb) {
                    const unsigned long long* rp = rowmat + (size_t)((w << 6) + bpos[s]) * NW;
                    rlo[s] = rp[lane];
                    rhi[s] = (lane < NW - 64) ? rp[64 + lane] : 0ULL;
                }
            }
            // serial greedy resolve within batch: diagonal words only (registers)
#pragma unroll
            for (int s = 0; s < 8; ++s) {
                if (s < nb) {
                    unsigned long long bit = 1ULL << bpos[s];
                    if (live & bit) {   // still unsuppressed -> keep it
                        unsigned long long diag = (w < 64) ? __shfl(rlo[s], w, 64)
                                                           : __shfl(rhi[s], w - 64, 64);
                        if (lane == 0) keptArr[kept] = (w << 6) + bpos[s];
                        kept++;
                        live &= ~bit;
                        live &= ~diag;      // within-word suppression (bits j>i only)
                        m0 |= rlo[s];       // full-row suppression for later words
                        m1 |= rhi[s];
                        if (kept == POSTN) { live = 0; w = NW; }
                    } else {
                        live &= ~bit;       // suppressed earlier in this batch
                    }
                }
            }
        }
    }
    __syncthreads();
    for (int k = lane; k < POSTN; k += 64) {
        float4 bb = make_float4(0.f, 0.f, 0.f, 0.f);
        if (k < kept) bb = sortedbox[keptArr[k]];
        out[k * 5 + 0] = 0.0f;
        out[k * 5 + 1] = bb.x;
        out[k * 5 + 2] = bb.y;
        out[k * 5 + 3] = bb.z;
        out[k * 5 + 4] = bb.w;
    }
}

extern "C" void kernel_launch(void* const* d_in, const int* in_sizes, int n_in,
                              void* d_out, int out_size, void* d_ws, size_t ws_size,
                              hipStream_t stream) {
    const float* scores = (const float*)d_in[0];
    const float* deltas = (const float*)d_in[1];
    const float* iminfo = (const float*)d_in[2];
    char* w = (char*)d_ws;
    // workspace layout (~4.95 MB). rowmat ALIASES boxes+skeys (dead after sort).
    float4*   boxes = (float4*)w;                                   // [0, 3538944)
    unsigned* skeys = (unsigned*)(w + 3538944);                     // [3538944, 4423680)
    unsigned long long* rowmat = (unsigned long long*)w;            // [0, 4524032)  alias
    unsigned* hist  = (unsigned*)(w + 4524032);                     // [4524032, 4786176)
    unsigned* meta  = (unsigned*)(w + 4786176);                     // 16 words (contig after hist)
    unsigned long long* cbuf = (unsigned long long*)(w + 4786240);  // [4786240, 4851776)
    float4* sortedbox = (float4*)(w + 4851776);                     // [4851776, 4948032)
    unsigned long long* initmask = (unsigned long long*)(w + 4948032); // 94 words
    float* out = (float*)d_out;

    hipMemsetAsync(hist, 0, (NBIN + 16) * sizeof(unsigned), stream);  // hist + meta
    decode_kernel<<<NCELL / 256, 256, 0, stream>>>(scores, deltas, iminfo, boxes, skeys, hist);
    thresh_kernel<<<1, 256, 0, stream>>>(hist, meta);
    compact_kernel<<<(NTOT + 255) / 256, 256, 0, stream>>>(skeys, meta, cbuf);
    sort_kernel<<<1, 1024, 0, stream>>>(boxes, meta, cbuf, sortedbox, initmask);
    matrix_kernel<<<NPADR / 16, 256, 0, stream>>>(sortedbox, rowmat);
    scan_kernel<<<1, 64, 0, stream>>>(rowmat, sortedbox, initmask, out);
}

// Round 4
// 350.549 us; speedup vs baseline: 1.2862x; 1.2862x over previous
//
#include <hip/hip_runtime.h>

#define NCELL 24576      // 128*192 feature cells
#define NTOT  221184     // NCELL * 9
#define NBIN  65536
#define TOPN  6000
#define POSTN 300
#define CAP   8192       // compaction capacity
#define NPADR 6016       // padded candidate count (94 words of 64)
#define NW    94         // suppression-mask words per row
#define CHUNK_W 8        // words per scan chunk (512 ranks)
#define NCHUNK 12        // ceil(94/8)

// ---------------- decode anchors + scores, build sort keys, histogram ----------------
__global__ void decode_kernel(const float* __restrict__ scores,
                              const float* __restrict__ deltas,
                              const float* __restrict__ iminfo,
                              float4* __restrict__ boxes,
                              unsigned* __restrict__ skeys,
                              unsigned* __restrict__ hist) {
#pragma clang fp contract(off)
    int c = blockIdx.x * blockDim.x + threadIdx.x;
    if (c >= NCELL) return;
    const float AW[9] = {184.f,368.f,736.f,128.f,256.f,512.f, 88.f,176.f,352.f};
    const float AH[9] = { 96.f,192.f,384.f,128.f,256.f,512.f,176.f,352.f,704.f};
    float sx = (float)((c >> 7) << 4);   // (c/128)*16  -- 'ij' meshgrid quirk
    float sy = (float)((c & 127) << 4);  // (c%128)*16
    float imh = iminfo[0], imw = iminfo[1], ims = iminfo[2];
    float xhi = imw - 1.0f, yhi = imh - 1.0f;
    float ms = 16.0f * ims;
    float ctrx = sx + 8.0f, ctry = sy + 8.0f;
    const float* sbase = scores + 9 * NCELL + c;
    const float* dbase = deltas + c;
#pragma unroll
    for (int a = 0; a < 9; ++a) {
        float sc = sbase[a * NCELL];
        float dx = dbase[(4 * a + 0) * NCELL];
        float dy = dbase[(4 * a + 1) * NCELL];
        float dw = dbase[(4 * a + 2) * NCELL];
        float dh = dbase[(4 * a + 3) * NCELL];
        float pcx = dx * AW[a] + ctrx;
        float pcy = dy * AH[a] + ctry;
        float pw = expf(dw) * AW[a];
        float ph = expf(dh) * AH[a];
        float x1 = pcx - 0.5f * pw;
        float y1 = pcy - 0.5f * ph;
        float x2 = pcx + 0.5f * pw;
        float y2 = pcy + 0.5f * ph;
        x1 = fminf(fmaxf(x1, 0.0f), xhi);
        x2 = fminf(fmaxf(x2, 0.0f), xhi);
        y1 = fminf(fmaxf(y1, 0.0f), yhi);
        y2 = fminf(fmaxf(y2, 0.0f), yhi);
        bool valid = ((x2 - x1 + 1.0f) >= ms) && ((y2 - y1 + 1.0f) >= ms);
        unsigned u = __float_as_uint(sc);
        unsigned key = (u & 0x80000000u) ? ~u : (u | 0x80000000u);
        if (!valid) key = 0x007FFFFFu;   // sort key of -inf
        boxes[a * NCELL + c] = make_float4(x1, y1, x2, y2);
        skeys[a * NCELL + c] = key;
        atomicAdd(&hist[key >> 16], 1u);
    }
}

// ---------------- find threshold bin T: cum(>T) < 6000 <= cum(>=T) ----------------
__global__ void thresh_kernel(const unsigned* __restrict__ hist, unsigned* __restrict__ meta) {
    __shared__ unsigned csum[256];
    __shared__ unsigned sB, sAbove;
    int tid = threadIdx.x;
    const uint4* h4 = (const uint4*)hist;
    unsigned s = 0;
#pragma unroll 8
    for (int q = 0; q < 64; ++q) {
        uint4 u = h4[tid * 64 + q];
        s += u.x + u.y + u.z + u.w;
    }
    csum[tid] = s;
    __syncthreads();
    if (tid < 64) {
        int lane = tid;
        unsigned c0 = csum[lane * 4 + 0], c1 = csum[lane * 4 + 1];
        unsigned c2 = csum[lane * 4 + 2], c3 = csum[lane * 4 + 3];
        unsigned ls = c0 + c1 + c2 + c3;
        unsigned v = ls;
#pragma unroll
        for (int o = 1; o < 64; o <<= 1) {
            unsigned t = __shfl_down(v, o, 64);
            if (lane + o < 64) v += t;
        }
        unsigned sufExcl = v - ls;   // sum over coarse bins of lanes > lane
        unsigned a3 = sufExcl;
        unsigned a2 = a3 + c3;
        unsigned a1 = a2 + c2;
        unsigned a0 = a1 + c1;
        if (a0 < TOPN && a0 + c0 >= TOPN) { sB = lane * 4 + 0; sAbove = a0; }
        if (a1 < TOPN && a1 + c1 >= TOPN) { sB = lane * 4 + 1; sAbove = a1; }
        if (a2 < TOPN && a2 + c2 >= TOPN) { sB = lane * 4 + 2; sAbove = a2; }
        if (a3 < TOPN && a3 + c3 >= TOPN) { sB = lane * 4 + 3; sAbove = a3; }
    }
    __syncthreads();
    if (tid < 64) {
        int lane = tid;
        unsigned B = sB, above = sAbove;
        uint4 f = h4[B * 64 + lane];       // fine bins B*256 + lane*4 + (0..3)
        unsigned ls = f.x + f.y + f.z + f.w;
        unsigned v = ls;
#pragma unroll
        for (int o = 1; o < 64; o <<= 1) {
            unsigned t = __shfl_down(v, o, 64);
            if (lane + o < 64) v += t;
        }
        unsigned sufExcl = v - ls;
        unsigned b3 = above + sufExcl;
        unsigned b2 = b3 + f.w;
        unsigned b1 = b2 + f.z;
        unsigned b0 = b1 + f.y;
        unsigned base2 = B * 256 + lane * 4;
        if (b0 < TOPN && b0 + f.x >= TOPN) meta[1] = base2 + 0;
        if (b1 < TOPN && b1 + f.y >= TOPN) meta[1] = base2 + 1;
        if (b2 < TOPN && b2 + f.z >= TOPN) meta[1] = base2 + 2;
        if (b3 < TOPN && b3 + f.w >= TOPN) meta[1] = base2 + 3;
    }
}

// ---------------- compact all candidates with key_hi >= T ----------------
__global__ void compact_kernel(const unsigned* __restrict__ skeys,
                               unsigned* __restrict__ meta,
                               unsigned long long* __restrict__ cbuf) {
    int m = blockIdx.x * blockDim.x + threadIdx.x;
    if (m >= NTOT) return;
    unsigned T = meta[1];
    unsigned sk = skeys[m];
    if ((sk >> 16) >= T) {
        unsigned pos = atomicAdd(&meta[0], 1u);
        if (pos < CAP) {
            unsigned n = (unsigned)((m % NCELL) * 9 + (m / NCELL));  // original flat index
            cbuf[pos] = ((unsigned long long)sk << 32) | (unsigned long long)(~n);
        }
    }
}

// ---------------- rank by counting: rank_i = #{key_j > key_i} (grid-parallel) ----------------
__global__ __launch_bounds__(256) void rank_kernel(const unsigned long long* __restrict__ cbuf,
                                                   const unsigned* __restrict__ meta,
                                                   unsigned* __restrict__ rank) {
    __shared__ unsigned long long jk[512];
    unsigned count = meta[0];
    if (count > (unsigned)CAP) count = CAP;
    int jt = blockIdx.x, it = blockIdx.y;
    int tid = threadIdx.x;
#pragma unroll
    for (int q = 0; q < 2; ++q) {
        int j = (jt << 9) + (q << 8) + tid;
        jk[(q << 8) + tid] = (j < (int)count) ? cbuf[j] : 0ULL;  // 0 never > any real key
    }
    __syncthreads();
#pragma unroll
    for (int q = 0; q < 2; ++q) {
        int i = (it << 9) + (q << 8) + tid;
        if (i < (int)count) {
            unsigned long long ki = cbuf[i];
            unsigned c = 0;
#pragma unroll 8
            for (int j = 0; j < 512; ++j) c += (jk[j] > ki) ? 1u : 0u;
            atomicAdd(&rank[i], c);
        }
    }
}

// ---------------- scatter boxes into rank order ----------------
__global__ void scatter_kernel(const unsigned long long* __restrict__ cbuf,
                               const unsigned* __restrict__ meta,
                               const unsigned* __restrict__ rank,
                               const float4* __restrict__ boxes,
                               float4* __restrict__ sortedbox) {
    int t = blockIdx.x * blockDim.x + threadIdx.x;
    unsigned count = meta[0];
    if (count > (unsigned)CAP) count = CAP;
    if (t >= (int)count) return;
    unsigned r = rank[t];
    if (r < NPADR) {
        unsigned n = ~(unsigned)cbuf[t];
        unsigned m = (n % 9u) * (unsigned)NCELL + (n / 9u);
        sortedbox[r] = boxes[m];
    }
}

// ---------------- all-pairs suppression matrix: rowmat[i][w] bits j>i with iou>0.7 ----------------
__global__ __launch_bounds__(256) void matrix_kernel(const float4* __restrict__ sortedbox,
                                                     unsigned long long* __restrict__ rowmat) {
#pragma clang fp contract(off)
    __shared__ float4 rb[16];
    __shared__ float ra[16];
    int tid = threadIdx.x;
    int r0 = blockIdx.x * 16;
    if (tid < 16) {
        float4 v = sortedbox[r0 + tid];
        rb[tid] = v;
        ra[tid] = (v.z - v.x) * (v.w - v.y);
    }
    __syncthreads();
    int wave = tid >> 6, lane = tid & 63;
    for (int w = wave; w < NW; w += 4) {
        int j = (w << 6) + lane;
        float4 cb = sortedbox[j];
        float ca = (cb.z - cb.x) * (cb.w - cb.y);
#pragma unroll 4
        for (int rr = 0; rr < 16; ++rr) {
            int i = r0 + rr;
            if (((w << 6) + 63) <= i) {          // whole word is j<=i -> zero row word
                if (lane == 0) rowmat[(size_t)i * NW + w] = 0ULL;
                continue;
            }
            float4 bi = rb[rr];
            float ai = ra[rr];
            float iw = fminf(bi.z, cb.z) - fmaxf(bi.x, cb.x);
            float ih = fminf(bi.w, cb.w) - fmaxf(bi.y, cb.y);
            iw = fmaxf(iw, 0.0f);
            ih = fmaxf(ih, 0.0f);
            float inter = iw * ih;
            float denom = fmaxf(ai + ca - inter, 1e-9f);
            bool sup = (j > i) && (inter / denom > 0.7f);
            unsigned long long word = __ballot(sup);
            if (lane == 0) rowmat[(size_t)i * NW + w] = word;
        }
    }
}

// ---------------- chunked greedy scan: LDS diag blocks + LDS global mask ----------------
__global__ __launch_bounds__(256) void scan_kernel(const unsigned long long* __restrict__ rowmat,
                                                   const float4* __restrict__ sortedbox,
                                                   float* __restrict__ out) {
    __shared__ unsigned long long diag[512 * CHUNK_W];   // 32 KB
    __shared__ unsigned long long gm[128];               // global suppression mask (94 used)
    __shared__ int keptArr[POSTN];
    __shared__ int s_kept;
    int tid = threadIdx.x;
    if (tid < 128) gm[tid] = 0ULL;
    if (tid == 93) gm[93] = ~((1ULL << 48) - 1);   // ranks >= 6000 pre-suppressed
    if (tid == 0) s_kept = 0;
    // prologue: load diag block for chunk 0
    for (int e = tid; e < 512 * CHUNK_W; e += 256) {
        int r = e >> 3, wl = e & 7;
        diag[e] = rowmat[(size_t)r * NW + wl];
    }
    __syncthreads();

    int keptPrev = 0;
    for (int c = 0; c < NCHUNK; ++c) {
        int wbase = c * CHUNK_W;
        int nwords = NW - wbase; if (nwords > CHUNK_W) nwords = CHUNK_W;
        int rbase = wbase << 6;
        // ---- phase B: wave 0 resolves this chunk ----
        if (tid < 64) {
            int lane = tid;
            unsigned long long lv = (lane < nwords) ? ~gm[wbase + lane] : 0ULL;
            int keptLocal = s_kept;
            while (keptLocal < POSTN) {
                int pos = lv ? ((lane << 6) + __ffsll((unsigned long long)lv) - 1) : 0x7FFFFFFF;
#pragma unroll
                for (int o = 1; o < 8; o <<= 1) pos = min(pos, __shfl_xor(pos, o, 64));
                if (pos >= 0x10000) break;       // lanes 8-63 leave immediately; 0-7 when empty
                if (lane == 0) keptArr[keptLocal] = rbase + pos;
                keptLocal++;
                unsigned long long rw = (lane < nwords) ? diag[(pos << 3) + lane] : 0ULL;
                lv &= ~rw;
                if (lane == (pos >> 6)) lv &= ~(1ULL << (pos & 63));
            }
            if (tid == 0) s_kept = keptLocal;
        }
        __syncthreads();
        int keptNow = s_kept;
        bool done = (keptNow >= POSTN) || (c == NCHUNK - 1);
        if (!done) {
            // ---- phase A: prefetch next chunk's diag block ----
            int wb2 = wbase + CHUNK_W;
            int nw2 = NW - wb2; if (nw2 > CHUNK_W) nw2 = CHUNK_W;
            int rb2 = wb2 << 6;
            int tot = (nw2 << 6) * CHUNK_W;
            for (int e = tid; e < tot; e += 256) {
                int r = e >> 3, wl = e & 7;
                diag[e] = (wl < nw2) ? rowmat[(size_t)(rb2 + r) * NW + wb2 + wl] : 0ULL;
            }
            // ---- phase C: OR this chunk's kept rows' future words into gm (4 waves) ----
            int lane = tid & 63, q = tid >> 6;
            int wA = wbase + nwords + lane;
            int wB = wA + 64;
            unsigned long long accA = 0ULL, accB = 0ULL;
            for (int s = keptPrev + q; s < keptNow; s += 4) {
                size_t ro = (size_t)keptArr[s] * NW;
                if (wA < NW) accA |= rowmat[ro + wA];
                if (wB < NW) accB |= rowmat[ro + wB];
            }
            if (accA) atomicOr(&gm[wA], accA);
            if (accB) atomicOr(&gm[wB], accB);
        }
        keptPrev = keptNow;
        if (keptNow >= POSTN) break;
        __syncthreads();
    }
    __syncthreads();

    int kept = s_kept;
    for (int k = tid; k < POSTN; k += 256) {
        float4 bb = make_float4(0.f, 0.f, 0.f, 0.f);
        if (k < kept) bb = sortedbox[keptArr[k]];
        out[k * 5 + 0] = 0.0f;
        out[k * 5 + 1] = bb.x;
        out[k * 5 + 2] = bb.y;
        out[k * 5 + 3] = bb.z;
        out[k * 5 + 4] = bb.w;
    }
}

extern "C" void kernel_launch(void* const* d_in, const int* in_sizes, int n_in,
                              void* d_out, int out_size, void* d_ws, size_t ws_size,
                              hipStream_t stream) {
    const float* scores = (const float*)d_in[0];
    const float* deltas = (const float*)d_in[1];
    const float* iminfo = (const float*)d_in[2];
    char* w = (char*)d_ws;
    // workspace layout (~4.95 MB, same footprint as round 3):
    float4*   boxes = (float4*)w;                                   // [0, 3538944)
    unsigned* skeys = (unsigned*)(w + 3538944);                     // [3538944, 4423680)
    unsigned* rank  = (unsigned*)(w + 3538944);                     // aliases skeys (post-compact)
    unsigned long long* rowmat = (unsigned long long*)w;            // [0, 4524032) alias (post-scatter)
    unsigned* hist  = (unsigned*)(w + 4524032);                     // [4524032, 4786176)
    unsigned* meta  = (unsigned*)(w + 4786176);                     // 16 words
    unsigned long long* cbuf = (unsigned long long*)(w + 4786240);  // [4786240, 4851776)
    float4* sortedbox = (float4*)(w + 4851776);                     // [4851776, 4948032)
    float* out = (float*)d_out;

    hipMemsetAsync(hist, 0, NBIN * sizeof(unsigned) + 64, stream);  // hist + meta
    decode_kernel<<<NCELL / 256, 256, 0, stream>>>(scores, deltas, iminfo, boxes, skeys, hist);
    thresh_kernel<<<1, 256, 0, stream>>>(hist, meta);
    compact_kernel<<<(NTOT + 255) / 256, 256, 0, stream>>>(skeys, meta, cbuf);
    hipMemsetAsync(rank, 0, CAP * sizeof(unsigned), stream);        // skeys dead now
    rank_kernel<<<dim3(16, 16), 256, 0, stream>>>(cbuf, meta, rank);
    scatter_kernel<<<CAP / 256, 256, 0, stream>>>(cbuf, meta, rank, boxes, sortedbox);
    matrix_kernel<<<NPADR / 16, 256, 0, stream>>>(sortedbox, rowmat);
    scan_kernel<<<1, 256, 0, stream>>>(rowmat, sortedbox, out);
}